// Round 1
// baseline (697.451 us; speedup 1.0000x reference)
//
#include <hip/hip_runtime.h>
#include <hip/hip_bf16.h>

#define DMODEL 1024
#define NH 16
#define DKH 64
#define NB 4
#define SEQ 2048
#define MTOT (NB*SEQ)   // 8192

typedef __bf16 bf16_t;
typedef __bf16 bf16x8 __attribute__((ext_vector_type(8)));
typedef float f32x4 __attribute__((ext_vector_type(4)));

__device__ __forceinline__ float rmax16(float v) {
    v = fmaxf(v, __shfl_xor(v, 1));
    v = fmaxf(v, __shfl_xor(v, 2));
    v = fmaxf(v, __shfl_xor(v, 4));
    v = fmaxf(v, __shfl_xor(v, 8));
    return v;
}
__device__ __forceinline__ float rsum16(float v) {
    v += __shfl_xor(v, 1);
    v += __shfl_xor(v, 2);
    v += __shfl_xor(v, 4);
    v += __shfl_xor(v, 8);
    return v;
}

// NT GEMM: C[m][n] = sum_k A[m][k] * W[n][k] + bias[n]
// fp32 inputs, converted to bf16 during LDS staging; fp32 MFMA accumulate.
// OUT_MODE 0: write bf16 to head layout Qh[((b*NH+h)*SEQ+s)*DKH + d], m=b*SEQ+s, n=h*64+d
// OUT_MODE 1: write fp32 to out[m*N + n]
template<int OUT_MODE>
__global__ __launch_bounds__(256, 2)
void gemm_nt(const float* __restrict__ A, const float* __restrict__ W,
             const float* __restrict__ bias, void* __restrict__ out,
             int M, int N, int K)
{
    __shared__ bf16_t As[128][32];
    __shared__ bf16_t Ws[128][32];

    const int tid  = threadIdx.x;
    const int wave = tid >> 6;
    const int lane = tid & 63;
    const int ln   = lane & 15;
    const int quad = lane >> 4;
    const int wm   = (wave >> 1) * 64;
    const int wn   = (wave & 1) * 64;

    const int bm = blockIdx.x * 128;
    const int bn = blockIdx.y * 128;

    f32x4 acc[4][4] = {};

    for (int k0 = 0; k0 < K; k0 += 32) {
        // ---- stage 128x32 fp32 -> bf16 LDS for A and W ----
        #pragma unroll
        for (int i = 0; i < 4; ++i) {
            int idx = tid + i * 256;            // 0..1023
            int row = idx >> 3;                 // 0..127
            int c   = (idx & 7) * 4;            // 0,4,..28
            float4 av = *(const float4*)&A[(size_t)(bm + row) * K + k0 + c];
            float4 wv = *(const float4*)&W[(size_t)(bn + row) * K + k0 + c];
            union { bf16_t h[4]; uint2 u; } ta, tw;
            ta.h[0] = (bf16_t)av.x; ta.h[1] = (bf16_t)av.y;
            ta.h[2] = (bf16_t)av.z; ta.h[3] = (bf16_t)av.w;
            tw.h[0] = (bf16_t)wv.x; tw.h[1] = (bf16_t)wv.y;
            tw.h[2] = (bf16_t)wv.z; tw.h[3] = (bf16_t)wv.w;
            *(uint2*)&As[row][c] = ta.u;
            *(uint2*)&Ws[row][c] = tw.u;
        }
        __syncthreads();

        // ---- fragments + MFMA ----
        bf16x8 af[4], bfr[4];
        #pragma unroll
        for (int im = 0; im < 4; ++im)
            af[im] = *(const bf16x8*)&As[wm + im * 16 + ln][quad * 8];
        #pragma unroll
        for (int jn = 0; jn < 4; ++jn)
            bfr[jn] = *(const bf16x8*)&Ws[wn + jn * 16 + ln][quad * 8];
        #pragma unroll
        for (int im = 0; im < 4; ++im)
            #pragma unroll
            for (int jn = 0; jn < 4; ++jn)
                acc[im][jn] = __builtin_amdgcn_mfma_f32_16x16x32_bf16(
                    af[im], bfr[jn], acc[im][jn], 0, 0, 0);
        __syncthreads();
    }

    // ---- epilogue ----
    #pragma unroll
    for (int jn = 0; jn < 4; ++jn) {
        int n = bn + wn + jn * 16 + ln;
        float bv = bias[n];
        #pragma unroll
        for (int im = 0; im < 4; ++im) {
            #pragma unroll
            for (int r = 0; r < 4; ++r) {
                int m = bm + wm + im * 16 + quad * 4 + r;
                float v = acc[im][jn][r] + bv;
                if (OUT_MODE == 0) {
                    int b = m >> 11, s = m & (SEQ - 1);
                    int h = n >> 6, d = n & 63;
                    ((bf16_t*)out)[(((size_t)(b * NH + h)) * SEQ + s) * DKH + d] = (bf16_t)v;
                } else {
                    ((float*)out)[(size_t)m * N + n] = v;
                }
            }
        }
    }
}

// Flash attention, causal. One block = 64 Q rows of one (b,h); 4 waves x 16 rows.
// Q,K,V bf16 in (B,H,S,DK); X out fp32 in (B,S,H*DK).
__global__ __launch_bounds__(256, 2)
void attn_kernel(const bf16_t* __restrict__ Q, const bf16_t* __restrict__ Km,
                 const bf16_t* __restrict__ V, float* __restrict__ X)
{
    __shared__ bf16_t Ks[64][64];
    __shared__ bf16_t Vs[64][72];       // padded to break PV bank conflicts
    __shared__ bf16_t Ps[4][16][72];    // per-wave P tile

    const int tid  = threadIdx.x;
    const int wave = tid >> 6;
    const int lane = tid & 63;
    const int ln   = lane & 15;
    const int quad = lane >> 4;

    const int qt = blockIdx.x;          // 0..31  (q tile of 64 rows)
    const int bh = blockIdx.y;          // 0..63
    const int q0 = qt * 64;
    const size_t base = (size_t)bh * SEQ * DKH;

    // Q fragments for this wave's 16 rows (reused across all K tiles)
    const bf16_t* qrow = Q + base + (size_t)(q0 + wave * 16 + ln) * DKH;
    bf16x8 aq0 = *(const bf16x8*)(qrow + quad * 8);
    bf16x8 aq1 = *(const bf16x8*)(qrow + 32 + quad * 8);

    f32x4 oacc[4] = {};
    float mrow[4] = {-1e30f, -1e30f, -1e30f, -1e30f};
    float lrow[4] = {0.f, 0.f, 0.f, 0.f};

    for (int kt = 0; kt <= qt; ++kt) {
        const int j0 = kt * 64;
        __syncthreads();
        // stage K and V tiles (64x64 bf16 each)
        #pragma unroll
        for (int i = 0; i < 2; ++i) {
            int idx = tid + i * 256;        // 0..511
            int row = idx >> 3;             // 0..63
            int c8  = (idx & 7) * 8;        // 0,8,..56
            *(uint4*)&Ks[row][c8] = *(const uint4*)(Km + base + (size_t)(j0 + row) * DKH + c8);
            *(uint4*)&Vs[row][c8] = *(const uint4*)(V  + base + (size_t)(j0 + row) * DKH + c8);
        }
        __syncthreads();

        // S = Q K^T  (per wave: 16 x 64)
        f32x4 s[4] = {};
        #pragma unroll
        for (int jn = 0; jn < 4; ++jn) {
            bf16x8 bk0 = *(const bf16x8*)&Ks[jn * 16 + ln][quad * 8];
            bf16x8 bk1 = *(const bf16x8*)&Ks[jn * 16 + ln][32 + quad * 8];
            s[jn] = __builtin_amdgcn_mfma_f32_16x16x32_bf16(aq0, bk0, s[jn], 0, 0, 0);
            s[jn] = __builtin_amdgcn_mfma_f32_16x16x32_bf16(aq1, bk1, s[jn], 0, 0, 0);
        }

        const bool diag = (kt == qt);
        #pragma unroll
        for (int jn = 0; jn < 4; ++jn) {
            #pragma unroll
            for (int r = 0; r < 4; ++r) {
                float v = s[jn][r] * 0.125f;   // 1/sqrt(64)
                if (diag) {
                    int col = j0 + jn * 16 + ln;
                    int row = q0 + wave * 16 + quad * 4 + r;
                    if (col > row) v = -1e30f;
                }
                s[jn][r] = v;
            }
        }

        // online softmax per row
        #pragma unroll
        for (int r = 0; r < 4; ++r) {
            float mx = fmaxf(fmaxf(s[0][r], s[1][r]), fmaxf(s[2][r], s[3][r]));
            mx = rmax16(mx);
            float mn = fmaxf(mrow[r], mx);
            float alpha = __expf(mrow[r] - mn);
            float sum = 0.f;
            #pragma unroll
            for (int jn = 0; jn < 4; ++jn) {
                float p = __expf(s[jn][r] - mn);
                s[jn][r] = p;
                sum += p;
            }
            sum = rsum16(sum);
            lrow[r] = lrow[r] * alpha + sum;
            mrow[r] = mn;
            #pragma unroll
            for (int jn = 0; jn < 4; ++jn) oacc[jn][r] *= alpha;
        }

        // write P (bf16) to per-wave LDS tile
        #pragma unroll
        for (int r = 0; r < 4; ++r)
            #pragma unroll
            for (int jn = 0; jn < 4; ++jn)
                Ps[wave][quad * 4 + r][jn * 16 + ln] = (bf16_t)s[jn][r];
        __syncthreads();

        // O += P V
        bf16x8 ap0 = *(const bf16x8*)&Ps[wave][ln][quad * 8];
        bf16x8 ap1 = *(const bf16x8*)&Ps[wave][ln][32 + quad * 8];
        #pragma unroll
        for (int nj = 0; nj < 4; ++nj) {
            bf16x8 bv0, bv1;
            #pragma unroll
            for (int j = 0; j < 8; ++j) {
                bv0[j] = Vs[quad * 8 + j][nj * 16 + ln];
                bv1[j] = Vs[32 + quad * 8 + j][nj * 16 + ln];
            }
            oacc[nj] = __builtin_amdgcn_mfma_f32_16x16x32_bf16(ap0, bv0, oacc[nj], 0, 0, 0);
            oacc[nj] = __builtin_amdgcn_mfma_f32_16x16x32_bf16(ap1, bv1, oacc[nj], 0, 0, 0);
        }
    }

    // epilogue: X[(b*SEQ+s)*DMODEL + h*64 + d]  (fp32)
    const int bb = bh >> 4, hh = bh & 15;
    #pragma unroll
    for (int r = 0; r < 4; ++r) {
        int sg = q0 + wave * 16 + quad * 4 + r;
        float inv = 1.f / lrow[r];
        #pragma unroll
        for (int nj = 0; nj < 4; ++nj) {
            X[((size_t)(bb * SEQ + sg)) * DMODEL + hh * DKH + nj * 16 + ln] =
                oacc[nj][r] * inv;
        }
    }
}

extern "C" void kernel_launch(void* const* d_in, const int* in_sizes, int n_in,
                              void* d_out, int out_size, void* d_ws, size_t ws_size,
                              hipStream_t stream)
{
    const float* query = (const float*)d_in[0];
    const float* key   = (const float*)d_in[1];
    const float* value = (const float*)d_in[2];
    // d_in[3] = mask (causal tril, assumed)
    const float* Wq = (const float*)d_in[4];
    const float* bq = (const float*)d_in[5];
    const float* Wk = (const float*)d_in[6];
    const float* bk = (const float*)d_in[7];
    const float* Wv = (const float*)d_in[8];
    const float* bv = (const float*)d_in[9];
    const float* Wo = (const float*)d_in[10];
    const float* bo = (const float*)d_in[11];
    float* out = (float*)d_out;

    // workspace layout: Qh/Kh/Vh bf16 (16 MB each) + X fp32 (32 MB) = 80 MB
    char* ws = (char*)d_ws;
    bf16_t* Qh = (bf16_t*)(ws);
    bf16_t* Kh = (bf16_t*)(ws + ((size_t)16 << 20));
    bf16_t* Vh = (bf16_t*)(ws + ((size_t)32 << 20));
    float*  X  = (float*) (ws + ((size_t)48 << 20));

    dim3 gg(MTOT / 128, DMODEL / 128);  // 64 x 8
    dim3 bb(256);
    gemm_nt<0><<<gg, bb, 0, stream>>>(query, Wq, bq, Qh, MTOT, DMODEL, DMODEL);
    gemm_nt<0><<<gg, bb, 0, stream>>>(key,   Wk, bk, Kh, MTOT, DMODEL, DMODEL);
    gemm_nt<0><<<gg, bb, 0, stream>>>(value, Wv, bv, Vh, MTOT, DMODEL, DMODEL);

    attn_kernel<<<dim3(SEQ / 64, NB * NH), bb, 0, stream>>>(Qh, Kh, Vh, X);

    gemm_nt<1><<<gg, bb, 0, stream>>>(X, Wo, bo, out, MTOT, DMODEL, DMODEL);
}

// Round 2
// 559.227 us; speedup vs baseline: 1.2472x; 1.2472x over previous
//
#include <hip/hip_runtime.h>
#include <hip/hip_bf16.h>

#define DMODEL 1024
#define NH 16
#define DKH 64
#define NB 4
#define SEQ 2048
#define MTOT (NB*SEQ)   // 8192

typedef __bf16 bf16_t;
typedef __bf16 bf16x8 __attribute__((ext_vector_type(8)));
typedef float f32x4 __attribute__((ext_vector_type(4)));

__device__ __forceinline__ float rmax16(float v) {
    v = fmaxf(v, __shfl_xor(v, 1));
    v = fmaxf(v, __shfl_xor(v, 2));
    v = fmaxf(v, __shfl_xor(v, 4));
    v = fmaxf(v, __shfl_xor(v, 8));
    return v;
}
__device__ __forceinline__ float rsum16(float v) {
    v += __shfl_xor(v, 1);
    v += __shfl_xor(v, 2);
    v += __shfl_xor(v, 4);
    v += __shfl_xor(v, 8);
    return v;
}

// NT GEMM: C[m][n] = (sum_k A[m][k]*W[n][k] + bias[n]) * scale
// fp32 inputs, converted to bf16 during LDS staging; MFMA bf16.
// OUT_MODE 0: bf16 head layout  out[((b*NH+h)*SEQ+s)*DKH + d]
// OUT_MODE 1: fp32 row-major    out[m*N + n]
// OUT_MODE 2: bf16 transposed-head layout out[((b*NH+h)*DKH+d)*SEQ + s]
template<int OUT_MODE>
__global__ __launch_bounds__(256, 2)
void gemm_nt(const float* __restrict__ A, const float* __restrict__ W,
             const float* __restrict__ bias, void* __restrict__ out,
             int M, int N, int K, float scale)
{
    // pad to 40 elems (80 B = 20 words): fragment-read rows land on
    // rotating bank sets -> 2-way (free) instead of 8-way at stride 32.
    __shared__ bf16_t As[128][40];
    __shared__ bf16_t Ws[128][40];

    const int tid  = threadIdx.x;
    const int wave = tid >> 6;
    const int lane = tid & 63;
    const int ln   = lane & 15;
    const int quad = lane >> 4;
    const int wm   = (wave >> 1) * 64;
    const int wn   = (wave & 1) * 64;

    const int bm = blockIdx.x * 128;
    const int bn = blockIdx.y * 128;

    f32x4 acc[4][4] = {};

    for (int k0 = 0; k0 < K; k0 += 32) {
        // ---- stage 128x32 fp32 -> bf16 LDS for A and W (b128 LDS writes) ----
        #pragma unroll
        for (int i = 0; i < 2; ++i) {
            int idx = tid + i * 256;            // 0..511
            int row = idx >> 2;                 // 0..127
            int c   = (idx & 3) * 8;            // 0,8,16,24
            const float* ap = &A[(size_t)(bm + row) * K + k0 + c];
            const float* wp = &W[(size_t)(bn + row) * K + k0 + c];
            float4 a0 = *(const float4*)ap;
            float4 a1 = *(const float4*)(ap + 4);
            float4 w0 = *(const float4*)wp;
            float4 w1 = *(const float4*)(wp + 4);
            union { bf16_t h[8]; uint4 u; } ta, tw;
            ta.h[0]=(bf16_t)a0.x; ta.h[1]=(bf16_t)a0.y; ta.h[2]=(bf16_t)a0.z; ta.h[3]=(bf16_t)a0.w;
            ta.h[4]=(bf16_t)a1.x; ta.h[5]=(bf16_t)a1.y; ta.h[6]=(bf16_t)a1.z; ta.h[7]=(bf16_t)a1.w;
            tw.h[0]=(bf16_t)w0.x; tw.h[1]=(bf16_t)w0.y; tw.h[2]=(bf16_t)w0.z; tw.h[3]=(bf16_t)w0.w;
            tw.h[4]=(bf16_t)w1.x; tw.h[5]=(bf16_t)w1.y; tw.h[6]=(bf16_t)w1.z; tw.h[7]=(bf16_t)w1.w;
            *(uint4*)&As[row][c] = ta.u;
            *(uint4*)&Ws[row][c] = tw.u;
        }
        __syncthreads();

        bf16x8 af[4], bfr[4];
        #pragma unroll
        for (int im = 0; im < 4; ++im)
            af[im] = *(const bf16x8*)&As[wm + im * 16 + ln][quad * 8];
        #pragma unroll
        for (int jn = 0; jn < 4; ++jn)
            bfr[jn] = *(const bf16x8*)&Ws[wn + jn * 16 + ln][quad * 8];
        #pragma unroll
        for (int im = 0; im < 4; ++im)
            #pragma unroll
            for (int jn = 0; jn < 4; ++jn)
                acc[im][jn] = __builtin_amdgcn_mfma_f32_16x16x32_bf16(
                    af[im], bfr[jn], acc[im][jn], 0, 0, 0);
        __syncthreads();
    }

    #pragma unroll
    for (int jn = 0; jn < 4; ++jn) {
        int n = bn + wn + jn * 16 + ln;
        float bv = bias[n];
        #pragma unroll
        for (int im = 0; im < 4; ++im) {
            #pragma unroll
            for (int r = 0; r < 4; ++r) {
                int m = bm + wm + im * 16 + quad * 4 + r;
                float v = (acc[im][jn][r] + bv) * scale;
                if (OUT_MODE == 0) {
                    int b = m >> 11, s = m & (SEQ - 1);
                    int h = n >> 6, d = n & 63;
                    ((bf16_t*)out)[(((size_t)(b * NH + h)) * SEQ + s) * DKH + d] = (bf16_t)v;
                } else if (OUT_MODE == 2) {
                    int b = m >> 11, s = m & (SEQ - 1);
                    int h = n >> 6, d = n & 63;
                    ((bf16_t*)out)[(((size_t)(b * NH + h)) * DKH + d) * SEQ + s] = (bf16_t)v;
                } else {
                    ((float*)out)[(size_t)m * N + n] = v;
                }
            }
        }
    }
}

// Flash attention, causal. One block = 64 Q rows of one (b,h); 4 waves x 16 rows.
// Q (pre-scaled by 1/8), K in (B,H,S,DK) bf16; V TRANSPOSED in (B,H,DK,S) bf16.
// X out fp32 in (B,S,H*DK).
__global__ __launch_bounds__(256, 2)
void attn_kernel(const bf16_t* __restrict__ Q, const bf16_t* __restrict__ Km,
                 const bf16_t* __restrict__ Vt, float* __restrict__ X)
{
    __shared__ bf16_t Ks[64][72];      // [key row][d]   pad: 2-way banks
    __shared__ bf16_t Vts[64][72];     // [d][key row]   pad: 2-way banks
    __shared__ bf16_t Ps[4][16][72];   // per-wave P tile [q row][key row]

    const int tid  = threadIdx.x;
    const int wave = tid >> 6;
    const int lane = tid & 63;
    const int ln   = lane & 15;
    const int quad = lane >> 4;

    const int qt = gridDim.x - 1 - blockIdx.x;  // long blocks dispatch first
    const int bh = blockIdx.y;                  // 0..63
    const int q0 = qt * 64;
    const size_t base = (size_t)bh * SEQ * DKH;

    const bf16_t* qrow = Q + base + (size_t)(q0 + wave * 16 + ln) * DKH;
    bf16x8 aq0 = *(const bf16x8*)(qrow + quad * 8);
    bf16x8 aq1 = *(const bf16x8*)(qrow + 32 + quad * 8);

    f32x4 oacc[4] = {};
    float mrow[4] = {-1e30f, -1e30f, -1e30f, -1e30f};
    float lrow[4] = {0.f, 0.f, 0.f, 0.f};

    for (int kt = 0; kt <= qt; ++kt) {
        const int j0 = kt * 64;
        __syncthreads();   // prior PV done before restage
        #pragma unroll
        for (int i = 0; i < 2; ++i) {
            int idx = tid + i * 256;        // 0..511
            int row = idx >> 3;             // 0..63
            int c8  = (idx & 7) * 8;        // 0,8,..56
            *(uint4*)&Ks[row][c8]  = *(const uint4*)(Km + base + (size_t)(j0 + row) * DKH + c8);
            *(uint4*)&Vts[row][c8] = *(const uint4*)(Vt + base + (size_t)row * SEQ + j0 + c8);
        }
        __syncthreads();

        // S = Q K^T  (per wave: 16 x 64); Q pre-scaled by 1/sqrt(dk)
        f32x4 s[4] = {};
        #pragma unroll
        for (int jn = 0; jn < 4; ++jn) {
            bf16x8 bk0 = *(const bf16x8*)&Ks[jn * 16 + ln][quad * 8];
            bf16x8 bk1 = *(const bf16x8*)&Ks[jn * 16 + ln][32 + quad * 8];
            s[jn] = __builtin_amdgcn_mfma_f32_16x16x32_bf16(aq0, bk0, s[jn], 0, 0, 0);
            s[jn] = __builtin_amdgcn_mfma_f32_16x16x32_bf16(aq1, bk1, s[jn], 0, 0, 0);
        }

        if (kt == qt) {   // causal mask only on the diagonal tile
            #pragma unroll
            for (int jn = 0; jn < 4; ++jn) {
                int col = j0 + jn * 16 + ln;
                #pragma unroll
                for (int r = 0; r < 4; ++r) {
                    int row = q0 + wave * 16 + quad * 4 + r;
                    if (col > row) s[jn][r] = -1e30f;
                }
            }
        }

        // online softmax per row
        #pragma unroll
        for (int r = 0; r < 4; ++r) {
            float mx = fmaxf(fmaxf(s[0][r], s[1][r]), fmaxf(s[2][r], s[3][r]));
            mx = rmax16(mx);
            float mn = fmaxf(mrow[r], mx);
            float alpha = __expf(mrow[r] - mn);
            float sum = 0.f;
            #pragma unroll
            for (int jn = 0; jn < 4; ++jn) {
                float p = __expf(s[jn][r] - mn);
                s[jn][r] = p;
                sum += p;
            }
            sum = rsum16(sum);
            lrow[r] = lrow[r] * alpha + sum;
            mrow[r] = mn;
            #pragma unroll
            for (int jn = 0; jn < 4; ++jn) oacc[jn][r] *= alpha;
        }

        // write P (bf16) to per-wave LDS tile; no barrier needed (same-wave)
        #pragma unroll
        for (int r = 0; r < 4; ++r)
            #pragma unroll
            for (int jn = 0; jn < 4; ++jn)
                Ps[wave][quad * 4 + r][jn * 16 + ln] = (bf16_t)s[jn][r];

        // O += P V : all-vector LDS reads now (Vt layout)
        bf16x8 ap0 = *(const bf16x8*)&Ps[wave][ln][quad * 8];
        bf16x8 ap1 = *(const bf16x8*)&Ps[wave][ln][32 + quad * 8];
        #pragma unroll
        for (int nj = 0; nj < 4; ++nj) {
            bf16x8 bv0 = *(const bf16x8*)&Vts[nj * 16 + ln][quad * 8];
            bf16x8 bv1 = *(const bf16x8*)&Vts[nj * 16 + ln][32 + quad * 8];
            oacc[nj] = __builtin_amdgcn_mfma_f32_16x16x32_bf16(ap0, bv0, oacc[nj], 0, 0, 0);
            oacc[nj] = __builtin_amdgcn_mfma_f32_16x16x32_bf16(ap1, bv1, oacc[nj], 0, 0, 0);
        }
    }

    const int bb = bh >> 4, hh = bh & 15;
    #pragma unroll
    for (int r = 0; r < 4; ++r) {
        int sg = q0 + wave * 16 + quad * 4 + r;
        float inv = 1.f / lrow[r];
        #pragma unroll
        for (int nj = 0; nj < 4; ++nj) {
            X[((size_t)(bb * SEQ + sg)) * DMODEL + hh * DKH + nj * 16 + ln] =
                oacc[nj][r] * inv;
        }
    }
}

extern "C" void kernel_launch(void* const* d_in, const int* in_sizes, int n_in,
                              void* d_out, int out_size, void* d_ws, size_t ws_size,
                              hipStream_t stream)
{
    const float* query = (const float*)d_in[0];
    const float* key   = (const float*)d_in[1];
    const float* value = (const float*)d_in[2];
    const float* Wq = (const float*)d_in[4];
    const float* bq = (const float*)d_in[5];
    const float* Wk = (const float*)d_in[6];
    const float* bk = (const float*)d_in[7];
    const float* Wv = (const float*)d_in[8];
    const float* bv = (const float*)d_in[9];
    const float* Wo = (const float*)d_in[10];
    const float* bo = (const float*)d_in[11];
    float* out = (float*)d_out;

    char* ws = (char*)d_ws;
    bf16_t* Qh  = (bf16_t*)(ws);
    bf16_t* Kh  = (bf16_t*)(ws + ((size_t)16 << 20));
    bf16_t* Vth = (bf16_t*)(ws + ((size_t)32 << 20));
    float*  X   = (float*) (ws + ((size_t)48 << 20));

    dim3 gg(MTOT / 128, DMODEL / 128);
    dim3 bb(256);
    gemm_nt<0><<<gg, bb, 0, stream>>>(query, Wq, bq, Qh,  MTOT, DMODEL, DMODEL, 0.125f);
    gemm_nt<0><<<gg, bb, 0, stream>>>(key,   Wk, bk, Kh,  MTOT, DMODEL, DMODEL, 1.0f);
    gemm_nt<2><<<gg, bb, 0, stream>>>(value, Wv, bv, Vth, MTOT, DMODEL, DMODEL, 1.0f);

    attn_kernel<<<dim3(SEQ / 64, NB * NH), bb, 0, stream>>>(Qh, Kh, Vth, X);

    gemm_nt<1><<<gg, bb, 0, stream>>>(X, Wo, bo, out, MTOT, DMODEL, DMODEL, 1.0f);
}

// Round 3
// 484.262 us; speedup vs baseline: 1.4402x; 1.1548x over previous
//
#include <hip/hip_runtime.h>
#include <hip/hip_bf16.h>

#define DMODEL 1024
#define NH 16
#define DKH 64
#define NB 4
#define SEQ 2048
#define MTOT (NB*SEQ)   // 8192

typedef __bf16 bf16_t;
typedef __bf16 bf16x8 __attribute__((ext_vector_type(8)));
typedef float f32x4 __attribute__((ext_vector_type(4)));

__device__ __forceinline__ void async_copy16(void* lds, const void* g) {
    __builtin_amdgcn_global_load_lds(
        (const __attribute__((address_space(1))) unsigned int*)g,
        (__attribute__((address_space(3))) unsigned int*)lds, 16, 0, 0);
}

__device__ __forceinline__ float rmax16(float v) {
    v = fmaxf(v, __shfl_xor(v, 1));
    v = fmaxf(v, __shfl_xor(v, 2));
    v = fmaxf(v, __shfl_xor(v, 4));
    v = fmaxf(v, __shfl_xor(v, 8));
    return v;
}
__device__ __forceinline__ float rsum16(float v) {
    v += __shfl_xor(v, 1);
    v += __shfl_xor(v, 2);
    v += __shfl_xor(v, 4);
    v += __shfl_xor(v, 8);
    return v;
}

// fp32 -> bf16 elementwise; blockIdx.y selects tensor.
__global__ void cvt_kernel(const float* __restrict__ s0, const float* __restrict__ s1,
                           const float* __restrict__ s2, const float* __restrict__ s3,
                           bf16_t* __restrict__ d0, bf16_t* __restrict__ d1,
                           bf16_t* __restrict__ d2, bf16_t* __restrict__ d3, int n)
{
    const float* s = (blockIdx.y == 0) ? s0 : (blockIdx.y == 1) ? s1 :
                     (blockIdx.y == 2) ? s2 : s3;
    bf16_t* d = (blockIdx.y == 0) ? d0 : (blockIdx.y == 1) ? d1 :
                (blockIdx.y == 2) ? d2 : d3;
    int i = (blockIdx.x * 256 + threadIdx.x) * 8;
    if (i < n) {
        float4 a = *(const float4*)&s[i];
        float4 b = *(const float4*)&s[i + 4];
        union { bf16_t h[8]; uint4 u; } t;
        t.h[0]=(bf16_t)a.x; t.h[1]=(bf16_t)a.y; t.h[2]=(bf16_t)a.z; t.h[3]=(bf16_t)a.w;
        t.h[4]=(bf16_t)b.x; t.h[5]=(bf16_t)b.y; t.h[6]=(bf16_t)b.z; t.h[7]=(bf16_t)b.w;
        *(uint4*)&d[i] = t.u;
    }
}

// NT GEMM, bf16 inputs: C[m][n] = (sum_k A[m][k]*W[n][k] + bias[n]) * scale
// m97 structure: 128x128 tile, BK=64, global_load_lds 16B staging, unpadded LDS.
// OUT_MODE 0: bf16 head layout  out[((b*NH+h)*SEQ+s)*DKH + d]
// OUT_MODE 1: fp32 row-major    out[m*N + n]
// OUT_MODE 2: bf16 transposed-head layout out[((b*NH+h)*DKH+d)*SEQ + s]
template<int OUT_MODE>
__global__ __launch_bounds__(256, 2)
void gemm_bt(const bf16_t* __restrict__ A, const bf16_t* __restrict__ W,
             const float* __restrict__ bias, void* __restrict__ out,
             int M, int N, int K, float scale)
{
    __shared__ bf16_t As[128 * 64];
    __shared__ bf16_t Ws[128 * 64];

    const int tid  = threadIdx.x;
    const int wave = tid >> 6;
    const int lane = tid & 63;
    const int ln   = lane & 15;
    const int quad = lane >> 4;
    const int wm   = (wave >> 1) * 64;
    const int wn   = (wave & 1) * 64;
    const int bm   = blockIdx.x * 128;
    const int bn   = blockIdx.y * 128;
    const int srow = wave * 8 + (lane >> 3);   // staging row within 32-row group
    const int sg   = (lane & 7) * 8;           // staging col (elements)

    f32x4 acc[4][4] = {};

    for (int k0 = 0; k0 < K; k0 += 64) {
        #pragma unroll
        for (int rr = 0; rr < 4; ++rr) {
            int row = rr * 32 + srow;
            async_copy16(&As[(size_t)(rr * 32 + wave * 8) * 64],
                         &A[(size_t)(bm + row) * K + k0 + sg]);
            async_copy16(&Ws[(size_t)(rr * 32 + wave * 8) * 64],
                         &W[(size_t)(bn + row) * K + k0 + sg]);
        }
        __syncthreads();   // drains vmcnt (lds writes) before use

        bf16x8 af[2][4], wf[2][4];
        #pragma unroll
        for (int h = 0; h < 2; ++h) {
            #pragma unroll
            for (int t = 0; t < 4; ++t) {
                af[h][t] = *(const bf16x8*)&As[(wm + t * 16 + ln) * 64 + h * 32 + quad * 8];
                wf[h][t] = *(const bf16x8*)&Ws[(wn + t * 16 + ln) * 64 + h * 32 + quad * 8];
            }
        }
        #pragma unroll
        for (int h = 0; h < 2; ++h)
            #pragma unroll
            for (int im = 0; im < 4; ++im)
                #pragma unroll
                for (int jn = 0; jn < 4; ++jn)
                    acc[im][jn] = __builtin_amdgcn_mfma_f32_16x16x32_bf16(
                        af[h][im], wf[h][jn], acc[im][jn], 0, 0, 0);
        __syncthreads();
    }

    #pragma unroll
    for (int jn = 0; jn < 4; ++jn) {
        int n = bn + wn + jn * 16 + ln;
        float bv = bias[n];
        #pragma unroll
        for (int im = 0; im < 4; ++im) {
            #pragma unroll
            for (int r = 0; r < 4; ++r) {
                int m = bm + wm + im * 16 + quad * 4 + r;
                float v = (acc[im][jn][r] + bv) * scale;
                if (OUT_MODE == 0) {
                    int b = m >> 11, s = m & (SEQ - 1);
                    int h = n >> 6, d = n & 63;
                    ((bf16_t*)out)[(((size_t)(b * NH + h)) * SEQ + s) * DKH + d] = (bf16_t)v;
                } else if (OUT_MODE == 2) {
                    int b = m >> 11, s = m & (SEQ - 1);
                    int h = n >> 6, d = n & 63;
                    ((bf16_t*)out)[(((size_t)(b * NH + h)) * DKH + d) * SEQ + s] = (bf16_t)v;
                } else {
                    ((float*)out)[(size_t)m * N + n] = v;
                }
            }
        }
    }
}

// Flash attention, causal. One block = 128 Q rows of one (b,h); 4 waves, each
// owns 2 strips of 16 rows (strip so at rows so*64 + wave*16). K-tile = 64.
// Q (pre-scaled 1/8), K in (B,H,S,DK); V transposed (B,H,DK,S); X out bf16.
__global__ __launch_bounds__(256, 4)
void attn_kernel(const bf16_t* __restrict__ Q, const bf16_t* __restrict__ Km,
                 const bf16_t* __restrict__ Vt, bf16_t* __restrict__ X)
{
    __shared__ bf16_t Ks[64][72];
    __shared__ bf16_t Vts[64][72];
    __shared__ bf16_t Ps[4][32][72];

    const int tid  = threadIdx.x;
    const int wave = tid >> 6;
    const int lane = tid & 63;
    const int ln   = lane & 15;
    const int quad = lane >> 4;

    // scramble qt so a CU's co-resident blocks have staggered work sizes
    const int qt = (blockIdx.x + blockIdx.y + ((blockIdx.y >> 4) << 2)) & 15;
    const int bh = blockIdx.y;
    const int q0 = qt * 128;
    const size_t base = (size_t)bh * SEQ * DKH;

    bf16x8 aq[2][2];
    #pragma unroll
    for (int so = 0; so < 2; ++so) {
        const bf16_t* qr = Q + base + (size_t)(q0 + so * 64 + wave * 16 + ln) * DKH;
        aq[so][0] = *(const bf16x8*)(qr + quad * 8);
        aq[so][1] = *(const bf16x8*)(qr + 32 + quad * 8);
    }

    f32x4 oacc[2][4] = {};
    float mrow[2][4], lrow[2][4];
    #pragma unroll
    for (int so = 0; so < 2; ++so)
        #pragma unroll
        for (int r = 0; r < 4; ++r) { mrow[so][r] = -1e30f; lrow[so][r] = 0.f; }

    const int nkt = 2 * qt + 2;
    for (int kt = 0; kt < nkt; ++kt) {
        const int j0 = kt * 64;
        __syncthreads();
        #pragma unroll
        for (int i = 0; i < 2; ++i) {
            int idx = tid + i * 256;
            int row = idx >> 3;
            int c8  = (idx & 7) * 8;
            *(uint4*)&Ks[row][c8]  = *(const uint4*)(Km + base + (size_t)(j0 + row) * DKH + c8);
            *(uint4*)&Vts[row][c8] = *(const uint4*)(Vt + base + (size_t)row * SEQ + j0 + c8);
        }
        __syncthreads();

        #pragma unroll
        for (int so = 0; so < 2; ++so) {
            if (so == 0 && kt == nkt - 1) continue;   // fully masked tile

            f32x4 s[4] = {};
            #pragma unroll
            for (int jn = 0; jn < 4; ++jn) {
                bf16x8 bk0 = *(const bf16x8*)&Ks[jn * 16 + ln][quad * 8];
                bf16x8 bk1 = *(const bf16x8*)&Ks[jn * 16 + ln][32 + quad * 8];
                s[jn] = __builtin_amdgcn_mfma_f32_16x16x32_bf16(aq[so][0], bk0, s[jn], 0, 0, 0);
                s[jn] = __builtin_amdgcn_mfma_f32_16x16x32_bf16(aq[so][1], bk1, s[jn], 0, 0, 0);
            }

            const int rbase = q0 + so * 64 + wave * 16 + quad * 4;
            if (j0 + 63 > rbase + 3 || j0 + 63 > q0 + so * 64) {  // diagonal region
                #pragma unroll
                for (int jn = 0; jn < 4; ++jn) {
                    int col = j0 + jn * 16 + ln;
                    #pragma unroll
                    for (int r = 0; r < 4; ++r)
                        if (col > rbase + r) s[jn][r] = -1e30f;
                }
            }

            #pragma unroll
            for (int r = 0; r < 4; ++r) {
                float mx = fmaxf(fmaxf(s[0][r], s[1][r]), fmaxf(s[2][r], s[3][r]));
                mx = rmax16(mx);
                float mn = fmaxf(mrow[so][r], mx);
                float alpha = __expf(mrow[so][r] - mn);
                float sum = 0.f;
                #pragma unroll
                for (int jn = 0; jn < 4; ++jn) {
                    float p = __expf(s[jn][r] - mn);
                    s[jn][r] = p;
                    sum += p;
                }
                sum = rsum16(sum);
                lrow[so][r] = lrow[so][r] * alpha + sum;
                mrow[so][r] = mn;
                #pragma unroll
                for (int jn = 0; jn < 4; ++jn) oacc[so][jn][r] *= alpha;
            }

            #pragma unroll
            for (int r = 0; r < 4; ++r)
                #pragma unroll
                for (int jn = 0; jn < 4; ++jn)
                    Ps[wave][so * 16 + quad * 4 + r][jn * 16 + ln] = (bf16_t)s[jn][r];
        }

        // O += P V (per-wave LDS, no barrier needed)
        #pragma unroll
        for (int so = 0; so < 2; ++so) {
            if (so == 0 && kt == nkt - 1) continue;
            bf16x8 ap0 = *(const bf16x8*)&Ps[wave][so * 16 + ln][quad * 8];
            bf16x8 ap1 = *(const bf16x8*)&Ps[wave][so * 16 + ln][32 + quad * 8];
            #pragma unroll
            for (int nj = 0; nj < 4; ++nj) {
                bf16x8 bv0 = *(const bf16x8*)&Vts[nj * 16 + ln][quad * 8];
                bf16x8 bv1 = *(const bf16x8*)&Vts[nj * 16 + ln][32 + quad * 8];
                oacc[so][nj] = __builtin_amdgcn_mfma_f32_16x16x32_bf16(ap0, bv0, oacc[so][nj], 0, 0, 0);
                oacc[so][nj] = __builtin_amdgcn_mfma_f32_16x16x32_bf16(ap1, bv1, oacc[so][nj], 0, 0, 0);
            }
        }
    }

    const int bb = bh >> 4, hh = bh & 15;
    #pragma unroll
    for (int so = 0; so < 2; ++so) {
        #pragma unroll
        for (int r = 0; r < 4; ++r) {
            int sg = q0 + so * 64 + wave * 16 + quad * 4 + r;
            float inv = 1.f / lrow[so][r];
            #pragma unroll
            for (int nj = 0; nj < 4; ++nj)
                X[((size_t)(bb * SEQ + sg)) * DMODEL + hh * DKH + nj * 16 + ln] =
                    (bf16_t)(oacc[so][nj][r] * inv);
        }
    }
}

extern "C" void kernel_launch(void* const* d_in, const int* in_sizes, int n_in,
                              void* d_out, int out_size, void* d_ws, size_t ws_size,
                              hipStream_t stream)
{
    const float* query = (const float*)d_in[0];
    const float* key   = (const float*)d_in[1];
    const float* value = (const float*)d_in[2];
    const float* Wq = (const float*)d_in[4];
    const float* bq = (const float*)d_in[5];
    const float* Wk = (const float*)d_in[6];
    const float* bk = (const float*)d_in[7];
    const float* Wv = (const float*)d_in[8];
    const float* bv = (const float*)d_in[9];
    const float* Wo = (const float*)d_in[10];
    const float* bo = (const float*)d_in[11];
    float* out = (float*)d_out;

    // workspace aliasing plan (72 MB):
    //  [0,16)   qb   -> reused as Kh after gemmQ
    //  [16,32)  kb   -> reused as Vth after gemmK
    //  [32,48)  vb   -> reused as X  after gemmV
    //  [48,64)  Qh
    //  [64,72)  Wqb,Wkb,Wvb,Wob (2 MB each)
    char* ws = (char*)d_ws;
    bf16_t* qb  = (bf16_t*)(ws);
    bf16_t* kb  = (bf16_t*)(ws + ((size_t)16 << 20));
    bf16_t* vb  = (bf16_t*)(ws + ((size_t)32 << 20));
    bf16_t* Qh  = (bf16_t*)(ws + ((size_t)48 << 20));
    bf16_t* Wqb = (bf16_t*)(ws + ((size_t)64 << 20));
    bf16_t* Wkb = (bf16_t*)(ws + ((size_t)66 << 20));
    bf16_t* Wvb = (bf16_t*)(ws + ((size_t)68 << 20));
    bf16_t* Wob = (bf16_t*)(ws + ((size_t)70 << 20));
    bf16_t* Kh  = qb;
    bf16_t* Vth = kb;
    bf16_t* X   = vb;

    const int nAct = MTOT * DMODEL;     // 8388608
    const int nW   = DMODEL * DMODEL;   // 1048576
    cvt_kernel<<<dim3(nAct / 2048, 3), 256, 0, stream>>>(query, key, value, query,
                                                         qb, kb, vb, qb, nAct);
    cvt_kernel<<<dim3(nW / 2048, 4), 256, 0, stream>>>(Wq, Wk, Wv, Wo,
                                                       Wqb, Wkb, Wvb, Wob, nW);

    dim3 gg(MTOT / 128, DMODEL / 128);
    dim3 bt(256);
    gemm_bt<0><<<gg, bt, 0, stream>>>(qb, Wqb, bq, Qh,  MTOT, DMODEL, DMODEL, 0.125f);
    gemm_bt<0><<<gg, bt, 0, stream>>>(kb, Wkb, bk, Kh,  MTOT, DMODEL, DMODEL, 1.0f);
    gemm_bt<2><<<gg, bt, 0, stream>>>(vb, Wvb, bv, Vth, MTOT, DMODEL, DMODEL, 1.0f);

    attn_kernel<<<dim3(SEQ / 128, NB * NH), bt, 0, stream>>>(Qh, Kh, Vth, X);

    gemm_bt<1><<<gg, bt, 0, stream>>>(X, Wob, bo, out, MTOT, DMODEL, DMODEL, 1.0f);
}